// Round 3
// baseline (11544.857 us; speedup 1.0000x reference)
//
#include <hip/hip_runtime.h>
#include <hip/hip_bf16.h>
#include <stdint.h>

#define Bsz 512
#define Tsz 128
#define Fsz 512
#define Hsz 512
#define G3  1536   // 3H
#define KK  1024   // F + H (concat K)

typedef __attribute__((ext_vector_type(8))) short bf16x8;
typedef __attribute__((ext_vector_type(4))) float f32x4;

#define LDS_W   65536                   // hh weights: 2 col-tiles x 32 kb x 512 elems x 2B
#define LDS_RED 52224                   // 12 waves x 4 accs x 272 x 4B
#define LDS_TOT (LDS_W + LDS_RED)       // 117760 <= 160KB

__device__ __forceinline__ unsigned short f2bf(float x) {
    union { float f; unsigned int u; } v; v.f = x;
    unsigned int r = v.u + 0x7FFFu + ((v.u >> 16) & 1u);   // RNE
    return (unsigned short)(r >> 16);
}
__device__ __forceinline__ float fsigmoid(float x) { return 1.0f / (1.0f + __expf(-x)); }
__device__ __forceinline__ float ftanh(float x) { return 2.0f / (1.0f + __expf(-2.0f * x)) - 1.0f; }

// wTs[g][cT][kb][kg][l16][e] swizzled bf16 weights (fragment order; wave-load = lane*8)
__global__ void prep_w_kernel(const float* __restrict__ kern, const float* __restrict__ rkern,
                              unsigned short* __restrict__ wTs) {
    int idx = blockIdx.x * blockDim.x + threadIdx.x;   // exactly 3*512*1024 threads
    int e   = idx & 7;
    int l16 = (idx >> 3) & 15;
    int kg  = (idx >> 7) & 3;
    int kb  = (idx >> 9) & 31;
    int cT  = (idx >> 14) & 31;
    int g   = idx >> 19;
    int n = cT * 16 + l16;
    int k = kb * 32 + kg * 8 + e;
    float v = (k < Fsz) ? kern[(size_t)k * G3 + g * Hsz + n]
                        : rkern[(size_t)(k - Fsz) * G3 + g * Hsz + n];
    wTs[idx] = f2bf(v);
}

// xs[t][rT][kb][kg][l16][e] swizzled bf16 x (A-fragment order)
__global__ void convert_x_kernel(const float* __restrict__ x, unsigned short* __restrict__ xs) {
    const int nchunks = Bsz * Tsz * Fsz / 8;
    for (int c = blockIdx.x * blockDim.x + threadIdx.x; c < nchunks;
         c += gridDim.x * blockDim.x) {
        int l16 = c & 15;
        int kg  = (c >> 4) & 3;
        int kb  = (c >> 6) & 15;
        int rT  = (c >> 10) & 31;
        int t   = c >> 15;
        int b   = rT * 16 + l16;
        int f0  = kb * 32 + kg * 8;
        const float* src = x + ((size_t)b * Tsz + t) * Fsz + f0;
        float4 v0 = *reinterpret_cast<const float4*>(src);
        float4 v1 = *reinterpret_cast<const float4*>(src + 4);
        bf16x8 o;
        o[0] = (short)f2bf(v0.x); o[1] = (short)f2bf(v0.y);
        o[2] = (short)f2bf(v0.z); o[3] = (short)f2bf(v0.w);
        o[4] = (short)f2bf(v1.x); o[5] = (short)f2bf(v1.y);
        o[6] = (short)f2bf(v1.z); o[7] = (short)f2bf(v1.w);
        *reinterpret_cast<bf16x8*>(xs + (size_t)c * 8) = o;
    }
}

// Persistent GRU: 256 blocks (16 row-groups x 16 col-blocks), 1024 thr = 16 waves.
// Block tile: 32 rows x 32 h-cols. Wave (rt,ct,kq): rt=w>>3, ct=(w>>2)&1, kq=w&3.
// kq = K-quarter (256 of K=1024: x[128kq..) + h[128kq..)). z,r weights in VGPRs,
// hh weights in LDS. fp32 carry h in registers. Row-group barrier via atomic ctr
// (16 blocks/group, XCD-local under round-robin dispatch since blk%8 == rg%8... rg=blk&15).
__global__ __launch_bounds__(1024, 4) void gru_persistent(
    const unsigned short* __restrict__ xs,
    const unsigned short* __restrict__ wTs,
    unsigned short* __restrict__ hbuf,     // [2][Bsz*Hsz] swizzled bf16, double buffer
    float* __restrict__ hf,                // [Bsz][Hsz] final state fp32
    int* __restrict__ bar,                 // 16 counters, stride 16 ints
    const float* __restrict__ bias_i,
    const float* __restrict__ bias_r)
{
    extern __shared__ char smem[];
    unsigned short* hlds = (unsigned short*)smem;          // [2][32][512] hh weights
    float* red = (float*)(smem + LDS_W);                   // [12][4][272]

    const int tid  = threadIdx.x;
    const int lane = tid & 63;
    const int w    = tid >> 6;
    const int rt   = w >> 3;
    const int ct   = (w >> 2) & 1;
    const int kq   = w & 3;
    const int l16  = lane & 15;
    const int kg   = lane >> 4;
    const int blk  = blockIdx.x;
    const int rg   = blk & 15;         // row group (32 rows)
    const int cb   = blk >> 4;         // col block (32 h-cols)
    const int rT   = rg * 2 + rt;      // global 16-row tile for this wave
    const int n0   = cb * 32 + ct * 16;
    const int cTg  = cb * 2 + ct;      // global 16-col tile

    // ---- hh weights -> LDS (2 contiguous 32KB chunks from wTs g=2) ----
    #pragma unroll
    for (int ctl = 0; ctl < 2; ++ctl) {
        const unsigned short* src = wTs + ((size_t)(64 + cb * 2 + ctl) * 32) * 512;
        unsigned short* dst = hlds + ctl * 16384;
        for (int i = tid; i < 2048; i += 1024)
            *reinterpret_cast<bf16x8*>(dst + (size_t)i * 8) =
                *reinterpret_cast<const bf16x8*>(src + (size_t)i * 8);
    }
    // ---- z,r weights -> registers (8 K-frags each: 4 x-part + 4 h-part) ----
    bf16x8 wz[8], wrr[8];
    #pragma unroll
    for (int ii = 0; ii < 8; ++ii) {
        const int kbw = (ii < 4) ? (kq * 4 + ii) : (16 + kq * 4 + (ii - 4));
        wz[ii]  = *reinterpret_cast<const bf16x8*>(
            wTs + ((size_t)(0 * 32 + cTg) * 32 + kbw) * 512 + lane * 8);
        wrr[ii] = *reinterpret_cast<const bf16x8*>(
            wTs + ((size_t)(1 * 32 + cTg) * 32 + kbw) * 512 + lane * 8);
    }
    // biases (used by kq==0 epilogue waves)
    const int n = n0 + l16;
    const float bz_ = bias_i[n] + bias_r[n];
    const float br_ = bias_i[Hsz + n] + bias_r[Hsz + n];
    const float bih = bias_i[2 * Hsz + n];
    const float brh = bias_r[2 * Hsz + n];

    f32x4 hc = {0.f, 0.f, 0.f, 0.f};       // fp32 carry (this block's own tile)

    // prefetch x fragments for t=0
    bf16x8 xa[4];
    #pragma unroll
    for (int i = 0; i < 4; ++i)
        xa[i] = *reinterpret_cast<const bf16x8*>(
            xs + (((size_t)0 * 32 + rT) * 16 + (kq * 4 + i)) * 512 + lane * 8);

    __syncthreads();   // hlds ready

    int* cnt = bar + rg * 16;

    #pragma unroll 1
    for (int t = 0; t < Tsz; ++t) {
        f32x4 az = {0,0,0,0}, ar = {0,0,0,0}, ahx = {0,0,0,0}, ahh = {0,0,0,0};
        // ---- x-phase (independent of barrier) ----
        #pragma unroll
        for (int i = 0; i < 4; ++i) {
            bf16x8 bh = *reinterpret_cast<const bf16x8*>(
                hlds + ((size_t)(ct * 32 + kq * 4 + i)) * 512 + lane * 8);
            az  = __builtin_amdgcn_mfma_f32_16x16x32_bf16(xa[i], wz[i],  az,  0, 0, 0);
            ar  = __builtin_amdgcn_mfma_f32_16x16x32_bf16(xa[i], wrr[i], ar,  0, 0, 0);
            ahx = __builtin_amdgcn_mfma_f32_16x16x32_bf16(xa[i], bh,     ahx, 0, 0, 0);
        }
        // ---- wait for h_{t-1} from the 15 sibling blocks ----
        if (tid == 0) {
            const int target = 16 * t;
            int guard = 0;
            while (__hip_atomic_load(cnt, __ATOMIC_RELAXED, __HIP_MEMORY_SCOPE_AGENT) < target) {
                __builtin_amdgcn_s_sleep(2);
                if (++guard > (1 << 27)) break;   // safety: corrupt > hang
            }
        }
        __syncthreads();
        __threadfence();   // acquire: invalidate stale h lines
        // ---- h-phase ----
        const unsigned short* hrd = hbuf + (size_t)(t & 1) * (Bsz * Hsz);
        #pragma unroll
        for (int i = 0; i < 4; ++i) {
            bf16x8 a = *reinterpret_cast<const bf16x8*>(
                hrd + ((size_t)rT * 16 + kq * 4 + i) * 512 + lane * 8);
            bf16x8 bh = *reinterpret_cast<const bf16x8*>(
                hlds + ((size_t)(ct * 32 + 16 + kq * 4 + i)) * 512 + lane * 8);
            az  = __builtin_amdgcn_mfma_f32_16x16x32_bf16(a, wz[4 + i],  az,  0, 0, 0);
            ar  = __builtin_amdgcn_mfma_f32_16x16x32_bf16(a, wrr[4 + i], ar,  0, 0, 0);
            ahh = __builtin_amdgcn_mfma_f32_16x16x32_bf16(a, bh,         ahh, 0, 0, 0);
        }
        // ---- K-partial reduction ----
        if (kq != 0) {
            float* rp = red + (size_t)((rt * 2 + ct) * 3 + (kq - 1)) * 4 * 272;
            #pragma unroll
            for (int j = 0; j < 4; ++j) {
                const int ad = l16 * 17 + kg * 4 + j;
                rp[0 * 272 + ad] = az[j];
                rp[1 * 272 + ad] = ar[j];
                rp[2 * 272 + ad] = ahx[j];
                rp[3 * 272 + ad] = ahh[j];
            }
        }
        __syncthreads();
        // ---- epilogue (kq==0 waves) ----
        if (kq == 0) {
            unsigned short* hwr = hbuf + (size_t)((t + 1) & 1) * (Bsz * Hsz);
            const int kb_n = n >> 5, kg_n = (n >> 3) & 3, e_n = n & 7;
            const size_t wbase = ((size_t)rT * 16 + kb_n) * 512 + kg_n * 128 + e_n;
            #pragma unroll
            for (int j = 0; j < 4; ++j) {
                const int ad = l16 * 17 + kg * 4 + j;
                float zs = az[j], rs = ar[j], xh = ahx[j], hh2 = ahh[j];
                #pragma unroll
                for (int i = 0; i < 3; ++i) {
                    const float* rp = red + (size_t)((rt * 2 + ct) * 3 + i) * 4 * 272;
                    zs  += rp[0 * 272 + ad];
                    rs  += rp[1 * 272 + ad];
                    xh  += rp[2 * 272 + ad];
                    hh2 += rp[3 * 272 + ad];
                }
                float z  = fsigmoid(zs + bz_);
                float r  = fsigmoid(rs + br_);
                float hh = ftanh(xh + bih + r * (hh2 + brh));
                float hn = z * hc[j] + (1.0f - z) * hh;
                hc[j] = hn;
                hwr[wbase + (size_t)(kg * 4 + j) * 8] = f2bf(hn);
                if (t == Tsz - 1)
                    hf[(size_t)(rg * 32 + rt * 16 + kg * 4 + j) * Hsz + n] = hn;
            }
            __threadfence();   // release h writes
        }
        __syncthreads();
        if (tid == 0)
            __hip_atomic_fetch_add(cnt, 1, __ATOMIC_RELEASE, __HIP_MEMORY_SCOPE_AGENT);
        // ---- prefetch x for t+1 (hides under siblings' spin window) ----
        if (t < Tsz - 1) {
            #pragma unroll
            for (int i = 0; i < 4; ++i)
                xa[i] = *reinterpret_cast<const bf16x8*>(
                    xs + (((size_t)(t + 1) * 32 + rT) * 16 + (kq * 4 + i)) * 512 + lane * 8);
        }
    }
}

// out[b] = h[b,:] . dense_w + dense_b   (one wave per batch row)
__global__ void dense_kernel(const float* __restrict__ h, const float* __restrict__ dw,
                             const float* __restrict__ db, float* __restrict__ out) {
    const int wid  = (blockIdx.x * blockDim.x + threadIdx.x) >> 6;
    const int lane = threadIdx.x & 63;
    if (wid >= Bsz) return;
    const float* hr = h + (size_t)wid * Hsz;
    float s = 0.f;
    #pragma unroll
    for (int i = 0; i < 2; ++i) {
        float4 hv = reinterpret_cast<const float4*>(hr)[lane * 2 + i];
        float4 wv = reinterpret_cast<const float4*>(dw)[lane * 2 + i];
        s += hv.x * wv.x + hv.y * wv.y + hv.z * wv.z + hv.w * wv.w;
    }
    #pragma unroll
    for (int off = 32; off > 0; off >>= 1) s += __shfl_down(s, off, 64);
    if (lane == 0) out[wid] = s + db[0];
}

extern "C" void kernel_launch(void* const* d_in, const int* in_sizes, int n_in,
                              void* d_out, int out_size, void* d_ws, size_t ws_size,
                              hipStream_t stream) {
    const float* x      = (const float*)d_in[0];
    const float* kern   = (const float*)d_in[1];
    const float* rkern  = (const float*)d_in[2];
    const float* bias_i = (const float*)d_in[3];
    const float* bias_r = (const float*)d_in[4];
    const float* dw     = (const float*)d_in[5];
    const float* db     = (const float*)d_in[6];
    float* out = (float*)d_out;

    char* ws = (char*)d_ws;
    size_t off = 0;
    unsigned short* wTs = (unsigned short*)(ws + off); off += (size_t)G3 * KK * 2;     // 3 MB
    unsigned short* hbuf = (unsigned short*)(ws + off); off += (size_t)2 * Bsz * Hsz * 2; // 1 MB
    float* hf = (float*)(ws + off); off += (size_t)Bsz * Hsz * 4;                      // 1 MB
    int* bar = (int*)(ws + off); off += 1024;
    unsigned short* xs = (unsigned short*)(ws + off);                                  // 64 MB

    prep_w_kernel<<<(G3 * KK) / 256, 256, 0, stream>>>(kern, rkern, wTs);
    hipMemsetAsync(hbuf, 0, (size_t)Bsz * Hsz * 2, stream);   // h_{-1} = 0 (buffer 0)
    hipMemsetAsync(bar, 0, 1024, stream);
    convert_x_kernel<<<4096, 256, 0, stream>>>(x, xs);

    hipFuncSetAttribute(reinterpret_cast<const void*>(gru_persistent),
                        hipFuncAttributeMaxDynamicSharedMemorySize, LDS_TOT);
    void* args[] = { (void*)&xs, (void*)&wTs, (void*)&hbuf, (void*)&hf,
                     (void*)&bar, (void*)&bias_i, (void*)&bias_r };
    hipError_t e = hipLaunchCooperativeKernel(reinterpret_cast<const void*>(gru_persistent),
                                              dim3(256), dim3(1024), args, LDS_TOT, stream);
    if (e != hipSuccess) {
        // fallback: grid == machine capacity (1 block/CU x 256 CUs), co-residency holds
        gru_persistent<<<dim3(256), dim3(1024), LDS_TOT, stream>>>(
            xs, wTs, hbuf, hf, bar, bias_i, bias_r);
    }
    dense_kernel<<<Bsz / 4, 256, 0, stream>>>(hf, dw, db, out);
}

// Round 4
// 1003.241 us; speedup vs baseline: 11.5076x; 11.5076x over previous
//
#include <hip/hip_runtime.h>
#include <hip/hip_bf16.h>
#include <stdint.h>

#define Bsz 512
#define Tsz 128
#define Fsz 512
#define Hsz 512
#define G3  1536

typedef __attribute__((ext_vector_type(8))) short bf16x8;
typedef __attribute__((ext_vector_type(4))) float f32x4;

#define AS1 __attribute__((address_space(1)))
#define AS3 __attribute__((address_space(3)))

__device__ __forceinline__ unsigned short f2bf(float x) {
    union { float f; unsigned int u; } v; v.f = x;
    unsigned int r = v.u + 0x7FFFu + ((v.u >> 16) & 1u);   // RNE
    return (unsigned short)(r >> 16);
}
__device__ __forceinline__ float bf2f(unsigned short u) {
    union { float f; unsigned int i; } v; v.i = ((unsigned int)u) << 16; return v.f;
}
__device__ __forceinline__ float fsigmoid(float x) { return 1.0f / (1.0f + __expf(-x)); }
__device__ __forceinline__ float ftanh(float x) { return 2.0f / (1.0f + __expf(-2.0f * x)) - 1.0f; }

// system-coherent (cross-XCD safe) 16B load/store
__device__ __forceinline__ bf16x8 load_b128_sc(const unsigned short* p) {
    bf16x8 v;
    asm volatile("global_load_dwordx4 %0, %1, off sc0 sc1" : "=v"(v) : "v"(p) : "memory");
    return v;
}
__device__ __forceinline__ void store_b128_sc(unsigned short* p, bf16x8 v) {
    asm volatile("global_store_dwordx4 %0, %1, off sc0 sc1" :: "v"(p), "v"(v) : "memory");
}

// x fp32 [B][T][F] -> xbf bf16, same flat order (row m = b*T+t, k = f)
__global__ void convert_x_kernel(const float* __restrict__ x, unsigned short* __restrict__ xbf) {
    const int nchunks = Bsz * Tsz * Fsz / 8;
    for (int c = blockIdx.x * blockDim.x + threadIdx.x; c < nchunks;
         c += gridDim.x * blockDim.x) {
        const float* src = x + (size_t)c * 8;
        float4 v0 = *reinterpret_cast<const float4*>(src);
        float4 v1 = *reinterpret_cast<const float4*>(src + 4);
        bf16x8 o;
        o[0] = (short)f2bf(v0.x); o[1] = (short)f2bf(v0.y);
        o[2] = (short)f2bf(v0.z); o[3] = (short)f2bf(v0.w);
        o[4] = (short)f2bf(v1.x); o[5] = (short)f2bf(v1.y);
        o[6] = (short)f2bf(v1.z); o[7] = (short)f2bf(v1.w);
        *reinterpret_cast<bf16x8*>(xbf + (size_t)c * 8) = o;
    }
}

// wTp[n][k] = kernel[k][n] bf16  (n in [0,1536), k in [0,512))
__global__ void prep_wp_kernel(const float* __restrict__ kern, unsigned short* __restrict__ wTp) {
    int idx = blockIdx.x * blockDim.x + threadIdx.x;   // 786432 threads
    int k = idx / G3;
    int n = idx - k * G3;
    wTp[(size_t)n * 512 + k] = f2bf(kern[(size_t)k * G3 + n]);
}

// wTr swizzled: elem (g, n, k) -> ((g*32+cT)*16 + kb)*512 + kg*128 + l16*8 + e
//   cT=n>>4 l16=n&15 kb=k>>5 kg=(k>>3)&3 e=k&7   (K = 512)
__global__ void prep_wr_kernel(const float* __restrict__ rkern, unsigned short* __restrict__ wTr) {
    int idx = blockIdx.x * blockDim.x + threadIdx.x;   // 786432 threads
    int k = idx / G3;
    int gc = idx - k * G3;
    int g = gc >> 9, n = gc & 511;
    int cT = n >> 4, l16 = n & 15;
    int kb = k >> 5, kg = (k >> 3) & 3, e = k & 7;
    float v = rkern[(size_t)k * G3 + gc];
    wTr[((size_t)((g * 32 + cT) * 16 + kb)) * 512 + kg * 128 + l16 * 8 + e] = f2bf(v);
}

// x_proj GEMM: C[m][n] = A[m][k]*Bt[n][k], M=65536 N=1536 K=512, bf16 in/out fp32 acc.
// 128x128 tile, BK=64, 4 waves, global_load_lds w=16, XOR-swizzled LDS (byte^((row&7)<<4)).
// Output written t-major: xp[(t*512 + b)*1536 + n], with m = b*128 + t.
__global__ __launch_bounds__(256) void xproj_gemm(
    const unsigned short* __restrict__ A, const unsigned short* __restrict__ Bt,
    unsigned short* __restrict__ xp)
{
    __shared__ unsigned short As[128 * 64], Bs[128 * 64];
    const int tid = threadIdx.x, lane = tid & 63, w = tid >> 6;
    const int l16 = lane & 15, kg = lane >> 4;
    const int bm = blockIdx.x, bn = blockIdx.y;
    const int wr = (w >> 1) * 64, wc = (w & 1) * 64;

    f32x4 acc[4][4];
    #pragma unroll
    for (int i = 0; i < 4; ++i)
        #pragma unroll
        for (int j = 0; j < 4; ++j) acc[i][j] = (f32x4){0.f, 0.f, 0.f, 0.f};

    for (int kt = 0; kt < 8; ++kt) {
        #pragma unroll
        for (int c2 = 0; c2 < 4; ++c2) {
            const int o = c2 * 4096 + tid * 16;          // byte offset in 16KB tile
            const int r = o >> 7, cc = o & 127;
            const int sw = (cc ^ ((r & 7) << 4)) >> 1;   // swizzled k-elem offset
            const int base = (o & ~1023) >> 1;           // wave-uniform LDS elem base
            __builtin_amdgcn_global_load_lds(
                (const AS1 unsigned int*)(const void*)(A + (size_t)(bm * 128 + r) * 512 + kt * 64 + sw),
                (AS3 unsigned int*)(void*)(As + base), 16, 0, 0);
            __builtin_amdgcn_global_load_lds(
                (const AS1 unsigned int*)(const void*)(Bt + (size_t)(bn * 128 + r) * 512 + kt * 64 + sw),
                (AS3 unsigned int*)(void*)(Bs + base), 16, 0, 0);
        }
        __syncthreads();
        #pragma unroll
        for (int kk = 0; kk < 2; ++kk) {
            const int kb2 = (kk * 64 + kg * 16) ^ ((l16 & 7) << 4);
            bf16x8 a[4], b[4];
            #pragma unroll
            for (int mf = 0; mf < 4; ++mf)
                a[mf] = *reinterpret_cast<const bf16x8*>(
                    (const char*)As + (wr + mf * 16 + l16) * 128 + kb2);
            #pragma unroll
            for (int nf = 0; nf < 4; ++nf)
                b[nf] = *reinterpret_cast<const bf16x8*>(
                    (const char*)Bs + (wc + nf * 16 + l16) * 128 + kb2);
            #pragma unroll
            for (int mf = 0; mf < 4; ++mf)
                #pragma unroll
                for (int nf = 0; nf < 4; ++nf)
                    acc[mf][nf] = __builtin_amdgcn_mfma_f32_16x16x32_bf16(a[mf], b[nf], acc[mf][nf], 0, 0, 0);
        }
        __syncthreads();
    }
    #pragma unroll
    for (int mf = 0; mf < 4; ++mf)
        #pragma unroll
        for (int j = 0; j < 4; ++j) {
            const int m = bm * 128 + wr + mf * 16 + kg * 4 + j;
            const int b = m >> 7, t = m & 127;
            unsigned short* dst = xp + ((size_t)t * 512 + b) * G3 + bn * 128 + wc + l16;
            #pragma unroll
            for (int nf = 0; nf < 4; ++nf)
                dst[nf * 16] = f2bf(acc[mf][nf][j]);
        }
}

// Persistent GRU recurrence. 256 blocks x 512 thr (8 waves), 1 block/CU (all resident).
// Block (rg=blk&15, cb=blk>>4): rows rg*32..+32, h-cols cb*32..+32. Wave (ct=w&1, kq=w>>1):
// kq = K-quarter of 512. Weights (rkernel only) in VGPRs: 12 bf16x8/wave. fp32 carry in regs.
// h exchanged via ring buffer (fresh addresses every step -> no stale caches) with sc0/sc1
// system-coherent b128 ops. Flags: relaxed AGENT atomics, 2 adds/block/step. NO fences.
__global__ __launch_bounds__(512, 2) void gru_persistent(
    const unsigned short* __restrict__ xp,    // [T][512][1536] bf16 (x@kernel, no bias)
    const unsigned short* __restrict__ wTr,   // swizzled rkernel
    unsigned short* __restrict__ hring,       // [T+1][512*512] swizzled bf16
    float* __restrict__ hf,                   // [512][512] final fp32
    int* __restrict__ cnt_,                   // 16 counters stride 16 ints
    const float* __restrict__ bias_i,
    const float* __restrict__ bias_r)
{
    __shared__ float red[6][3][2][256];       // [(kq-1)*2+ct][gate][rt][l16*16+kg*4+j]
    __shared__ unsigned short hpack[32 * 32];

    const int tid = threadIdx.x, lane = tid & 63, w = tid >> 6;
    const int ct = w & 1, kq = w >> 1;
    const int l16 = lane & 15, kg = lane >> 4;
    const int rg = blockIdx.x & 15, cb = blockIdx.x >> 4;
    const int cTg = cb * 2 + ct;

    bf16x8 wf[3][4];
    #pragma unroll
    for (int g = 0; g < 3; ++g)
        #pragma unroll
        for (int i = 0; i < 4; ++i)
            wf[g][i] = *reinterpret_cast<const bf16x8*>(
                wTr + ((size_t)((g * 32 + cTg) * 16 + kq * 4 + i)) * 512 + lane * 8);

    const int n = cb * 32 + ct * 16 + l16;
    const float bz_  = bias_i[n] + bias_r[n];
    const float brr_ = bias_i[512 + n] + bias_r[512 + n];
    const float bih  = bias_i[1024 + n];
    const float brh  = bias_r[1024 + n];

    f32x4 hc[2] = {{0.f,0.f,0.f,0.f},{0.f,0.f,0.f,0.f}};
    int* cnt = cnt_ + rg * 16;

    for (int t = 0; t < Tsz; ++t) {
        if (tid == 0) {
            const int target = 32 * t;
            int guard = 0;
            while (__hip_atomic_load(cnt, __ATOMIC_RELAXED, __HIP_MEMORY_SCOPE_AGENT) < target) {
                __builtin_amdgcn_s_sleep(2);
                if (++guard > (1 << 24)) break;   // corrupt > hang
            }
        }
        __syncthreads();                           // sync#1: h_t ready

        // xp prefetch (epilogue waves only) — plain loads, issued before the asm loads
        unsigned short xv[3][2][4];
        if (kq == 0) {
            #pragma unroll
            for (int g = 0; g < 3; ++g)
                #pragma unroll
                for (int rt = 0; rt < 2; ++rt)
                    #pragma unroll
                    for (int j = 0; j < 4; ++j) {
                        const int row = rg * 32 + rt * 16 + kg * 4 + j;
                        xv[g][rt][j] = xp[((size_t)t * 512 + row) * G3 + g * 512 + n];
                    }
        }

        // h A-fragments (ring slot t), system-coherent
        const unsigned short* hrd = hring + (size_t)t * 262144;
        bf16x8 hfr[2][4];
        #pragma unroll
        for (int rt = 0; rt < 2; ++rt)
            #pragma unroll
            for (int i = 0; i < 4; ++i)
                hfr[rt][i] = load_b128_sc(
                    hrd + ((size_t)((rg * 2 + rt) * 16 + kq * 4 + i)) * 512 + lane * 8);

        f32x4 az[2] = {{0.f,0.f,0.f,0.f},{0.f,0.f,0.f,0.f}};
        f32x4 ar[2] = {{0.f,0.f,0.f,0.f},{0.f,0.f,0.f,0.f}};
        f32x4 ah[2] = {{0.f,0.f,0.f,0.f},{0.f,0.f,0.f,0.f}};

        asm volatile("s_waitcnt vmcnt(4)" ::: "memory");   // xp + hfr[0] complete
        __builtin_amdgcn_sched_barrier(0);
        #pragma unroll
        for (int i = 0; i < 4; ++i) {
            az[0] = __builtin_amdgcn_mfma_f32_16x16x32_bf16(hfr[0][i], wf[0][i], az[0], 0, 0, 0);
            ar[0] = __builtin_amdgcn_mfma_f32_16x16x32_bf16(hfr[0][i], wf[1][i], ar[0], 0, 0, 0);
            ah[0] = __builtin_amdgcn_mfma_f32_16x16x32_bf16(hfr[0][i], wf[2][i], ah[0], 0, 0, 0);
        }
        asm volatile("s_waitcnt vmcnt(0)" ::: "memory");   // hfr[1] complete
        __builtin_amdgcn_sched_barrier(0);
        #pragma unroll
        for (int i = 0; i < 4; ++i) {
            az[1] = __builtin_amdgcn_mfma_f32_16x16x32_bf16(hfr[1][i], wf[0][i], az[1], 0, 0, 0);
            ar[1] = __builtin_amdgcn_mfma_f32_16x16x32_bf16(hfr[1][i], wf[1][i], ar[1], 0, 0, 0);
            ah[1] = __builtin_amdgcn_mfma_f32_16x16x32_bf16(hfr[1][i], wf[2][i], ah[1], 0, 0, 0);
        }

        if (kq != 0) {
            #pragma unroll
            for (int rt = 0; rt < 2; ++rt) {
                *reinterpret_cast<f32x4*>(&red[(kq - 1) * 2 + ct][0][rt][l16 * 16 + kg * 4]) = az[rt];
                *reinterpret_cast<f32x4*>(&red[(kq - 1) * 2 + ct][1][rt][l16 * 16 + kg * 4]) = ar[rt];
                *reinterpret_cast<f32x4*>(&red[(kq - 1) * 2 + ct][2][rt][l16 * 16 + kg * 4]) = ah[rt];
            }
        }
        __syncthreads();                           // sync#2: partials ready

        if (kq == 0) {
            #pragma unroll
            for (int rt = 0; rt < 2; ++rt) {
                f32x4 zs = az[rt], rs = ar[rt], hs = ah[rt];
                #pragma unroll
                for (int p = 0; p < 3; ++p) {
                    zs += *reinterpret_cast<const f32x4*>(&red[p * 2 + ct][0][rt][l16 * 16 + kg * 4]);
                    rs += *reinterpret_cast<const f32x4*>(&red[p * 2 + ct][1][rt][l16 * 16 + kg * 4]);
                    hs += *reinterpret_cast<const f32x4*>(&red[p * 2 + ct][2][rt][l16 * 16 + kg * 4]);
                }
                #pragma unroll
                for (int j = 0; j < 4; ++j) {
                    float z = fsigmoid(bf2f(xv[0][rt][j]) + zs[j] + bz_);
                    float r = fsigmoid(bf2f(xv[1][rt][j]) + rs[j] + brr_);
                    float hhv = ftanh(bf2f(xv[2][rt][j]) + bih + r * (hs[j] + brh));
                    float hn = z * hc[rt][j] + (1.0f - z) * hhv;
                    hc[rt][j] = hn;
                    hpack[(rt * 16 + kg * 4 + j) * 32 + ct * 16 + l16] = f2bf(hn);
                    if (t == Tsz - 1)
                        hf[(size_t)(rg * 32 + rt * 16 + kg * 4 + j) * 512 + n] = hn;
                }
            }
        }
        __syncthreads();                           // sync#3: hpack complete

        if (kq == 0) {
            const int rt = ct;                     // w0 stores rT0, w1 stores rT1
            bf16x8 pv = *reinterpret_cast<const bf16x8*>(hpack + (rt * 16 + l16) * 32 + kg * 8);
            store_b128_sc(hring + (size_t)(t + 1) * 262144 +
                          ((size_t)((rg * 2 + rt) * 16 + cb)) * 512 + lane * 8, pv);
            asm volatile("s_waitcnt vmcnt(0)" ::: "memory");
            if (lane == 0)
                __hip_atomic_fetch_add(cnt, 1, __ATOMIC_RELAXED, __HIP_MEMORY_SCOPE_AGENT);
        }
    }
}

// out[b] = h[b,:] . dense_w + dense_b
__global__ void dense_kernel(const float* __restrict__ h, const float* __restrict__ dw,
                             const float* __restrict__ db, float* __restrict__ out) {
    const int wid  = (blockIdx.x * blockDim.x + threadIdx.x) >> 6;
    const int lane = threadIdx.x & 63;
    if (wid >= Bsz) return;
    const float* hr = h + (size_t)wid * Hsz;
    float s = 0.f;
    #pragma unroll
    for (int i = 0; i < 2; ++i) {
        float4 hv = reinterpret_cast<const float4*>(hr)[lane * 2 + i];
        float4 wv = reinterpret_cast<const float4*>(dw)[lane * 2 + i];
        s += hv.x * wv.x + hv.y * wv.y + hv.z * wv.z + hv.w * wv.w;
    }
    #pragma unroll
    for (int off = 32; off > 0; off >>= 1) s += __shfl_down(s, off, 64);
    if (lane == 0) out[wid] = s + db[0];
}

extern "C" void kernel_launch(void* const* d_in, const int* in_sizes, int n_in,
                              void* d_out, int out_size, void* d_ws, size_t ws_size,
                              hipStream_t stream) {
    const float* x      = (const float*)d_in[0];
    const float* kern   = (const float*)d_in[1];
    const float* rkern  = (const float*)d_in[2];
    const float* bias_i = (const float*)d_in[3];
    const float* bias_r = (const float*)d_in[4];
    const float* dw     = (const float*)d_in[5];
    const float* db     = (const float*)d_in[6];
    float* out = (float*)d_out;

    char* ws = (char*)d_ws;
    size_t off = 0;
    unsigned short* wTp = (unsigned short*)(ws + off); off += (size_t)G3 * 512 * 2;        // 1.5 MB
    unsigned short* wTr = (unsigned short*)(ws + off); off += (size_t)G3 * 512 * 2;        // 1.5 MB
    unsigned short* xbf = (unsigned short*)(ws + off); off += (size_t)Bsz * Tsz * Fsz * 2; // 64 MB
    unsigned short* xp  = (unsigned short*)(ws + off); off += (size_t)Tsz * Bsz * G3 * 2;  // 192 MB
    unsigned short* hring = (unsigned short*)(ws + off); off += (size_t)(Tsz + 1) * Bsz * Hsz * 2; // 67.6 MB
    float* hf = (float*)(ws + off); off += (size_t)Bsz * Hsz * 4;                          // 1 MB
    int* cnt = (int*)(ws + off); off += 1024;

    convert_x_kernel<<<2048, 256, 0, stream>>>(x, xbf);
    prep_wp_kernel<<<3072, 256, 0, stream>>>(kern, wTp);
    prep_wr_kernel<<<3072, 256, 0, stream>>>(rkern, wTr);
    hipMemsetAsync(hring, 0, (size_t)Bsz * Hsz * 2, stream);   // h_0 = 0 (ring slot 0)
    hipMemsetAsync(cnt, 0, 1024, stream);

    xproj_gemm<<<dim3(512, 12), 256, 0, stream>>>(xbf, wTp, xp);
    gru_persistent<<<256, 512, 0, stream>>>(xp, wTr, hring, hf, cnt, bias_i, bias_r);
    dense_kernel<<<Bsz / 4, 256, 0, stream>>>(hf, dw, db, out);
}

// Round 6
// 719.261 us; speedup vs baseline: 16.0510x; 1.3948x over previous
//
#include <hip/hip_runtime.h>
#include <hip/hip_bf16.h>
#include <stdint.h>

#define Bsz 512
#define Tsz 128
#define Fsz 512
#define Hsz 512
#define G3  1536

typedef __attribute__((ext_vector_type(8))) short bf16x8;
typedef __attribute__((ext_vector_type(4))) float f32x4;
typedef __attribute__((ext_vector_type(2))) unsigned int u32x2;

#define AS1 __attribute__((address_space(1)))
#define AS3 __attribute__((address_space(3)))

#define SMEM_W   98304                 // 96 chunks x 512 bf16 = 96KB rkernel weights
#define SMEM_TOT (SMEM_W + 4 * 512)    // + 512B transpose scratch per wave (4 waves)

__device__ __forceinline__ unsigned short f2bf(float x) {
    union { float f; unsigned int u; } v; v.f = x;
    unsigned int r = v.u + 0x7FFFu + ((v.u >> 16) & 1u);   // RNE
    return (unsigned short)(r >> 16);
}
__device__ __forceinline__ float bf2f(unsigned short u) {
    union { float f; unsigned int i; } v; v.i = ((unsigned int)u) << 16; return v.f;
}
__device__ __forceinline__ float fsigmoid(float x) { return 1.0f / (1.0f + __expf(-x)); }
__device__ __forceinline__ float ftanh(float x) { return 2.0f / (1.0f + __expf(-2.0f * x)) - 1.0f; }

// system-coherent (cross-XCD safe) 16B load; no internal wait — caller stages vmcnt
__device__ __forceinline__ bf16x8 load_b128_sc(const unsigned short* p) {
    bf16x8 v;
    asm volatile("global_load_dwordx4 %0, %1, off sc0 sc1" : "=v"(v) : "v"(p) : "memory");
    return v;
}

// x fp32 [B][T][F] -> xbf bf16, same flat order
__global__ void convert_x_kernel(const float* __restrict__ x, unsigned short* __restrict__ xbf) {
    const int nchunks = Bsz * Tsz * Fsz / 8;
    for (int c = blockIdx.x * blockDim.x + threadIdx.x; c < nchunks;
         c += gridDim.x * blockDim.x) {
        const float* src = x + (size_t)c * 8;
        float4 v0 = *reinterpret_cast<const float4*>(src);
        float4 v1 = *reinterpret_cast<const float4*>(src + 4);
        bf16x8 o;
        o[0] = (short)f2bf(v0.x); o[1] = (short)f2bf(v0.y);
        o[2] = (short)f2bf(v0.z); o[3] = (short)f2bf(v0.w);
        o[4] = (short)f2bf(v1.x); o[5] = (short)f2bf(v1.y);
        o[6] = (short)f2bf(v1.z); o[7] = (short)f2bf(v1.w);
        *reinterpret_cast<bf16x8*>(xbf + (size_t)c * 8) = o;
    }
}

// wTp[n][k] = kernel[k][n] bf16
__global__ void prep_wp_kernel(const float* __restrict__ kern, unsigned short* __restrict__ wTp) {
    int idx = blockIdx.x * blockDim.x + threadIdx.x;
    int k = idx / G3;
    int n = idx - k * G3;
    wTp[(size_t)n * 512 + k] = f2bf(kern[(size_t)k * G3 + n]);
}

// wTr swizzled B-frag order: (g, n, k) -> ((g*32+cT)*16 + kb)*512 + kg*128 + l16*8 + e
__global__ void prep_wr_kernel(const float* __restrict__ rkern, unsigned short* __restrict__ wTr) {
    int idx = blockIdx.x * blockDim.x + threadIdx.x;
    int k = idx / G3;
    int gc = idx - k * G3;
    int g = gc >> 9, n = gc & 511;
    int cT = n >> 4, l16 = n & 15;
    int kb = k >> 5, kg = (k >> 3) & 3, e = k & 7;
    float v = rkern[(size_t)k * G3 + gc];
    wTr[((size_t)((g * 32 + cT) * 16 + kb)) * 512 + kg * 128 + l16 * 8 + e] = f2bf(v);
}

// x_proj GEMM: 128x128 tile, BK=64, 4 waves, global_load_lds w=16, XOR-swizzled LDS.
// grid (12, 512): 12 bn-tiles of one bm adjacent -> Bt (1.5MB) L2-resident, A fetched once.
__global__ __launch_bounds__(256) void xproj_gemm(
    const unsigned short* __restrict__ A, const unsigned short* __restrict__ Bt,
    unsigned short* __restrict__ xp)
{
    __shared__ unsigned short As[128 * 64], Bs[128 * 64];
    const int tid = threadIdx.x, lane = tid & 63, w = tid >> 6;
    const int l16 = lane & 15, kg = lane >> 4;
    const int bn = blockIdx.x, bm = blockIdx.y;
    const int wr = (w >> 1) * 64, wc = (w & 1) * 64;

    f32x4 acc[4][4];
    #pragma unroll
    for (int i = 0; i < 4; ++i)
        #pragma unroll
        for (int j = 0; j < 4; ++j) acc[i][j] = (f32x4){0.f, 0.f, 0.f, 0.f};

    for (int kt = 0; kt < 8; ++kt) {
        #pragma unroll
        for (int c2 = 0; c2 < 4; ++c2) {
            const int o = c2 * 4096 + tid * 16;
            const int r = o >> 7, cc = o & 127;
            const int sw = (cc ^ ((r & 7) << 4)) >> 1;
            const int base = (o & ~1023) >> 1;
            __builtin_amdgcn_global_load_lds(
                (const AS1 unsigned int*)(const void*)(A + (size_t)(bm * 128 + r) * 512 + kt * 64 + sw),
                (AS3 unsigned int*)(void*)(As + base), 16, 0, 0);
            __builtin_amdgcn_global_load_lds(
                (const AS1 unsigned int*)(const void*)(Bt + (size_t)(bn * 128 + r) * 512 + kt * 64 + sw),
                (AS3 unsigned int*)(void*)(Bs + base), 16, 0, 0);
        }
        __syncthreads();
        #pragma unroll
        for (int kk = 0; kk < 2; ++kk) {
            const int kb2 = (kk * 64 + kg * 16) ^ ((l16 & 7) << 4);
            bf16x8 a[4], b[4];
            #pragma unroll
            for (int mf = 0; mf < 4; ++mf)
                a[mf] = *reinterpret_cast<const bf16x8*>(
                    (const char*)As + (wr + mf * 16 + l16) * 128 + kb2);
            #pragma unroll
            for (int nf = 0; nf < 4; ++nf)
                b[nf] = *reinterpret_cast<const bf16x8*>(
                    (const char*)Bs + (wc + nf * 16 + l16) * 128 + kb2);
            #pragma unroll
            for (int mf = 0; mf < 4; ++mf)
                #pragma unroll
                for (int nf = 0; nf < 4; ++nf)
                    acc[mf][nf] = __builtin_amdgcn_mfma_f32_16x16x32_bf16(a[mf], b[nf], acc[mf][nf], 0, 0, 0);
        }
        __syncthreads();
    }
    #pragma unroll
    for (int mf = 0; mf < 4; ++mf)
        #pragma unroll
        for (int j = 0; j < 4; ++j) {
            const int m = bm * 128 + wr + mf * 16 + kg * 4 + j;
            const int b = m >> 7, t = m & 127;
            unsigned short* dst = xp + ((size_t)t * 512 + b) * G3 + bn * 128 + wc + l16;
            #pragma unroll
            for (int nf = 0; nf < 4; ++nf)
                dst[nf * 16] = f2bf(acc[mf][nf][j]);
        }
}

// Persistent GRU recurrence, v3: 256 blocks x 256 thr (4 waves), 1 block/CU.
// Block (rg=blk&15, cb=blk>>4) owns rows rg*32..+32, h-cols cb*32..+32. Wave (rt=w>>1,
// ct=w&1) owns one 16x16 output tile with FULL K=512 (48 MFMA): no K-split, no LDS
// reduction. rkernel (96KB) in LDS, read as conflict-free 1KB wave fragments.
// Sync skeleton = round-4-proven: tid0 sum-gate poll (provably lockstep: first passer
// of gate t forces all 16 counters = t) + 3 block barriers; h exchanged via ring buffer
// (fresh addresses each step) with sc0/sc1 asm ops; staged vmcnt(12/8/4/0) is safe:
// vmcnt(N) retires all but youngest N, and B1's pre-barrier drain zeroes the count.
__global__ __launch_bounds__(256, 1) void gru_persistent(
    const unsigned short* __restrict__ xp,    // [T][512][1536] bf16 (x@kernel, no bias)
    const unsigned short* __restrict__ wTr,   // swizzled rkernel
    unsigned short* __restrict__ hring,       // [T+1][512*512] A-frag-swizzled bf16
    float* __restrict__ hf,                   // [512][512] final fp32
    int* __restrict__ cnt_,                   // 16 counters stride 16 ints
    const float* __restrict__ bias_i,
    const float* __restrict__ bias_r)
{
    extern __shared__ char smem[];
    unsigned short* wlds = (unsigned short*)smem;                       // 96 x 1KB chunks

    const int tid = threadIdx.x, lane = tid & 63, w = tid >> 6;
    const int rt = w >> 1, ct = w & 1;
    const int l16 = lane & 15, kgd = lane >> 4;
    const int rg = blockIdx.x & 15, cb = blockIdx.x >> 4;
    const int rT16 = (rg * 2 + rt) * 16;
    const int rowbase = rg * 32 + rt * 16;
    unsigned short* scratch = (unsigned short*)(smem + SMEM_W) + w * 256;

    // ---- prologue: rkernel -> LDS (96 chunks, 24 per wave, linear gload_lds) ----
    #pragma unroll
    for (int i = 0; i < 24; ++i) {
        const int fi = w * 24 + i;                 // (g*2+ctc)*16 + kb
        const int g = fi >> 5, ctc = (fi >> 4) & 1, kb = fi & 15;
        const size_t gchunk = ((size_t)((g * 32 + cb * 2 + ctc) * 16 + kb)) * 512;
        __builtin_amdgcn_global_load_lds(
            (const AS1 unsigned int*)(const void*)(wTr + gchunk + lane * 8),
            (AS3 unsigned int*)(void*)(wlds + (size_t)fi * 512), 16, 0, 0);
    }

    const int n = cb * 32 + ct * 16 + l16;        // this lane's h-column
    const float bz_  = bias_i[n] + bias_r[n];
    const float brr_ = bias_i[512 + n] + bias_r[512 + n];
    const float bih  = bias_i[1024 + n];
    const float brh  = bias_r[1024 + n];

    __syncthreads();                               // wlds ready (barrier drains vmcnt)

    f32x4 hc = {0.f, 0.f, 0.f, 0.f};              // fp32 carry (wave's own 16x16 tile)
    int* cnt = cnt_ + rg * 16;

    // xp values for t=0 (plain compiler loads; compiler inserts its own waits)
    unsigned short xv[12];
    #pragma unroll
    for (int g = 0; g < 3; ++g)
        #pragma unroll
        for (int j = 0; j < 4; ++j)
            xv[g * 4 + j] = xp[((size_t)0 * 512 + rowbase + kgd * 4 + j) * G3 + g * 512 + n];

    #pragma unroll 1
    for (int t = 0; t < Tsz; ++t) {
        // ---- gate: slot t fully written (sum-gate forces lockstep at gates) ----
        if (tid == 0 && t > 0) {
            const int target = 16 * t;
            int guard = 0;
            while (__hip_atomic_load(cnt, __ATOMIC_RELAXED, __HIP_MEMORY_SCOPE_AGENT) < target) {
                __builtin_amdgcn_s_sleep(1);
                if (++guard > (1 << 26)) break;    // corrupt > hang
            }
        }
        __syncthreads();                           // B1: release; vmcnt drained -> clean count

        // ---- issue all 16 h A-frag loads (ring slot t), system-coherent ----
        const unsigned short* hrd = hring + (size_t)t * 262144;
        bf16x8 hfr[16];
        #pragma unroll
        for (int kb = 0; kb < 16; ++kb)
            hfr[kb] = load_b128_sc(hrd + (size_t)(rT16 + kb) * 512 + lane * 8);

        f32x4 az = {0.f,0.f,0.f,0.f}, arr = {0.f,0.f,0.f,0.f}, ahh = {0.f,0.f,0.f,0.f};

        // ---- 4 quarters: {12 ds_read B-frags | staged vmcnt | 12 MFMA} ----
        #pragma unroll
        for (int q = 0; q < 4; ++q) {
            bf16x8 bz[4], br[4], bh[4];
            #pragma unroll
            for (int i = 0; i < 4; ++i) {
                const int kb = q * 4 + i;
                bz[i] = *reinterpret_cast<const bf16x8*>(wlds + (size_t)((0 * 2 + ct) * 16 + kb) * 512 + lane * 8);
                br[i] = *reinterpret_cast<const bf16x8*>(wlds + (size_t)((1 * 2 + ct) * 16 + kb) * 512 + lane * 8);
                bh[i] = *reinterpret_cast<const bf16x8*>(wlds + (size_t)((2 * 2 + ct) * 16 + kb) * 512 + lane * 8);
            }
            if (q == 0)      asm volatile("s_waitcnt vmcnt(12)" ::: "memory");
            else if (q == 1) asm volatile("s_waitcnt vmcnt(8)"  ::: "memory");
            else if (q == 2) asm volatile("s_waitcnt vmcnt(4)"  ::: "memory");
            else             asm volatile("s_waitcnt vmcnt(0)"  ::: "memory");
            __builtin_amdgcn_sched_barrier(0);
            #pragma unroll
            for (int i = 0; i < 4; ++i) {
                az  = __builtin_amdgcn_mfma_f32_16x16x32_bf16(hfr[q * 4 + i], bz[i], az,  0, 0, 0);
                arr = __builtin_amdgcn_mfma_f32_16x16x32_bf16(hfr[q * 4 + i], br[i], arr, 0, 0, 0);
                ahh = __builtin_amdgcn_mfma_f32_16x16x32_bf16(hfr[q * 4 + i], bh[i], ahh, 0, 0, 0);
            }
        }

        // ---- in-wave epilogue (full-K sums: no reduction) ----
        #pragma unroll
        for (int j = 0; j < 4; ++j) {
            float z   = fsigmoid(bf2f(xv[0 + j]) + az[j]  + bz_);
            float r   = fsigmoid(bf2f(xv[4 + j]) + arr[j] + brr_);
            float hhv = ftanh(bf2f(xv[8 + j]) + bih + r * (ahh[j] + brh));
            float hn = z * hc[j] + (1.0f - z) * hhv;
            hc[j] = hn;
            // pack into A-frag order: idx = (col>>3)*128 + row*8 + (col&7); row=kgd*4+j, col=l16
            scratch[((l16 >> 3) << 7) + (kgd * 4 + j) * 8 + (l16 & 7)] = f2bf(hn);
            if (t == Tsz - 1)
                hf[(size_t)(rowbase + kgd * 4 + j) * 512 + n] = hn;
        }
        __syncthreads();                           // B2: scratch writes complete (lgkm drained)

        // ---- transpose readback + sc store of this wave's 512B chunk ----
        u32x2 pv = *reinterpret_cast<const u32x2*>(scratch + lane * 4);
        asm volatile("s_waitcnt lgkmcnt(0)" ::: "memory");
        __builtin_amdgcn_sched_barrier(0);
        unsigned short* dst = hring + (size_t)(t + 1) * 262144 +
                              (size_t)(rT16 + cb) * 512 + ct * 256 + lane * 4;
        asm volatile("global_store_dwordx2 %0, %1, off sc0 sc1" :: "v"(dst), "v"(pv) : "memory");
        asm volatile("s_waitcnt vmcnt(0)" ::: "memory");
        __syncthreads();                           // B3: all 4 waves' stores drained

        if (tid == 0)
            __hip_atomic_fetch_add(cnt, 1, __ATOMIC_RELAXED, __HIP_MEMORY_SCOPE_AGENT);

        // ---- prefetch xp for t+1 (compiler loads; overlap next poll window) ----
        if (t < Tsz - 1) {
            #pragma unroll
            for (int g = 0; g < 3; ++g)
                #pragma unroll
                for (int j = 0; j < 4; ++j)
                    xv[g * 4 + j] =
                        xp[((size_t)(t + 1) * 512 + rowbase + kgd * 4 + j) * G3 + g * 512 + n];
        }
    }
}

// out[b] = h[b,:] . dense_w + dense_b
__global__ void dense_kernel(const float* __restrict__ h, const float* __restrict__ dw,
                             const float* __restrict__ db, float* __restrict__ out) {
    const int wid  = (blockIdx.x * blockDim.x + threadIdx.x) >> 6;
    const int lane = threadIdx.x & 63;
    if (wid >= Bsz) return;
    const float* hr = h + (size_t)wid * Hsz;
    float s = 0.f;
    #pragma unroll
    for (int i = 0; i < 2; ++i) {
        float4 hv = reinterpret_cast<const float4*>(hr)[lane * 2 + i];
        float4 wv = reinterpret_cast<const float4*>(dw)[lane * 2 + i];
        s += hv.x * wv.x + hv.y * wv.y + hv.z * wv.z + hv.w * wv.w;
    }
    #pragma unroll
    for (int off = 32; off > 0; off >>= 1) s += __shfl_down(s, off, 64);
    if (lane == 0) out[wid] = s + db[0];
}

extern "C" void kernel_launch(void* const* d_in, const int* in_sizes, int n_in,
                              void* d_out, int out_size, void* d_ws, size_t ws_size,
                              hipStream_t stream) {
    const float* x      = (const float*)d_in[0];
    const float* kern   = (const float*)d_in[1];
    const float* rkern  = (const float*)d_in[2];
    const float* bias_i = (const float*)d_in[3];
    const float* bias_r = (const float*)d_in[4];
    const float* dw     = (const float*)d_in[5];
    const float* db     = (const float*)d_in[6];
    float* out = (float*)d_out;

    char* ws = (char*)d_ws;
    size_t off = 0;
    unsigned short* wTp = (unsigned short*)(ws + off); off += (size_t)G3 * 512 * 2;        // 1.5 MB
    unsigned short* wTr = (unsigned short*)(ws + off); off += (size_t)G3 * 512 * 2;        // 1.5 MB
    unsigned short* xbf = (unsigned short*)(ws + off); off += (size_t)Bsz * Tsz * Fsz * 2; // 64 MB
    unsigned short* xp  = (unsigned short*)(ws + off); off += (size_t)Tsz * Bsz * G3 * 2;  // 192 MB
    unsigned short* hring = (unsigned short*)(ws + off); off += (size_t)(Tsz + 1) * Bsz * Hsz * 2; // 64.5 MB
    float* hf = (float*)(ws + off); off += (size_t)Bsz * Hsz * 4;                          // 1 MB
    int* cnt = (int*)(ws + off); off += 1024;

    convert_x_kernel<<<2048, 256, 0, stream>>>(x, xbf);
    prep_wp_kernel<<<3072, 256, 0, stream>>>(kern, wTp);
    prep_wr_kernel<<<3072, 256, 0, stream>>>(rkern, wTr);
    hipMemsetAsync(hring, 0, (size_t)Bsz * Hsz * 2, stream);   // h_0 = 0 (ring slot 0)
    hipMemsetAsync(cnt, 0, 1024, stream);

    xproj_gemm<<<dim3(12, 512), 256, 0, stream>>>(xbf, wTp, xp);

    hipFuncSetAttribute(reinterpret_cast<const void*>(gru_persistent),
                        hipFuncAttributeMaxDynamicSharedMemorySize, SMEM_TOT);
    gru_persistent<<<256, 256, SMEM_TOT, stream>>>(xp, wTr, hring, hf, cnt, bias_i, bias_r);
    dense_kernel<<<Bsz / 4, 256, 0, stream>>>(hf, dw, db, out);
}